// Round 4
// baseline (920.502 us; speedup 1.0000x reference)
//
#include <hip/hip_runtime.h>
#include <math.h>

#define WGRID 128
#define HGRID 128
#define TSTEPS 500

// 4-round DPP butterfly within each 16-lane row: every lane ends with its row's sum.
__device__ __forceinline__ float dpp_sum16(float v) {
    int x;
    x = __builtin_amdgcn_update_dpp(0, __float_as_int(v), 0xB1, 0xF, 0xF, true);
    v += __int_as_float(x);
    x = __builtin_amdgcn_update_dpp(0, __float_as_int(v), 0x4E, 0xF, 0xF, true);
    v += __int_as_float(x);
    x = __builtin_amdgcn_update_dpp(0, __float_as_int(v), 0x141, 0xF, 0xF, true);
    v += __int_as_float(x);
    x = __builtin_amdgcn_update_dpp(0, __float_as_int(v), 0x140, 0xF, 0xF, true);
    v += __int_as_float(x);
    return v;
}

// Per-axis interp prep: index + fractional weight (clip to [0,126]).
// EXACT reference numerics: (q + 6.4f) / 0.1f with IEEE division.
struct Ax { int i0; float w; };
__device__ __forceinline__ Ax axq(float q) {
    float xi = (q + 6.4f) / 0.1f;
    xi = fminf(fmaxf(xi, 0.0f), 126.0f);
    float f = floorf(xi);
    Ax a; a.i0 = (int)f; a.w = xi - f; return a;
}

// One bilinear query: 4 corner loads (issued here, consumed next iteration) + weights.
struct Iq { float z00, z01, z10, z11, wx, wy; };
__device__ __forceinline__ Iq issueQ(const float* __restrict__ zb, Ax ax, Ax ay) {
    const float* r0 = zb + (ax.i0 * WGRID + ay.i0);
    Iq q;
    q.z00 = r0[0];
    q.z01 = r0[1];
    q.z10 = r0[WGRID];
    q.z11 = r0[WGRID + 1];
    q.wx = ax.w; q.wy = ay.w;
    return q;
}
__device__ __forceinline__ float combineQ(Iq q) {
    float ox = 1.0f - q.wx, oy = 1.0f - q.wy;
    return q.z00 * ox * oy + q.z10 * q.wx * oy + q.z01 * ox * q.wy + q.z11 * q.wx * q.wy;
}

extern "C" __global__ __launch_bounds__(64, 1) void dphys_sim(
    const float* __restrict__ z_grid,
    const float* __restrict__ controls,
    const float* __restrict__ robot_points,
    const float* __restrict__ I_inv,
    float* __restrict__ out)
{
    const int b = blockIdx.x;
    const int lane = threadIdx.x;

    const float* __restrict__ zb = z_grid + (size_t)b * (HGRID * WGRID);

    // I_inv: uniform -> SGPRs
    const float i00 = I_inv[0], i01 = I_inv[1], i02 = I_inv[2];
    const float i10 = I_inv[3], i11 = I_inv[4], i12 = I_inv[5];
    const float i20 = I_inv[6], i21 = I_inv[7], i22 = I_inv[8];

    // point for this lane (4x redundant across quarter-wave rows)
    const int p = lane & 15;
    const float rpx = robot_points[3 * p + 0];
    const float rpy = robot_points[3 * p + 1];
    const float rpz = robot_points[3 * p + 2];

    const float cog_y = dpp_sum16(rpy) * (1.0f / 16.0f);   // exact: ys are +-0.25
    const bool is_left = rpy > cog_y;

    const float K_STIFF = 5000.0f;
    const float K_DAMP  = 894.4271909999159f;   // sqrt(4*40*5000)
    const float K_FRIC  = 0.5f;
    const float EPSF    = 1e-6f;
    // rk4 with constant derivative: x + d*CRK, CRK = dt*(1+dt/2+dt^2/6+dt^3/24)
    const float CRK     = 0.010050166708416667f;

    // state (redundant per lane)
    float X = 0.f, Y = 0.f, Z = 1.f;
    float VX = 0.f, VY = 0.f, VZ = 0.f;
    float R00 = 1.f, R01 = 0.f, R02 = 0.f;
    float R10 = 0.f, R11 = 1.f, R12 = 0.f;
    float R20 = 0.f, R21 = 0.f, R22 = 1.f;
    float OX = 0.f, OY = 0.f, OZ = 0.f;
    float px = rpx, py = rpy, pz = rpz + 1.0f;
    float pvx = 0.f, pvy = 0.f, pvz = 0.f;

    float* outb = out + (size_t)b * TSTEPS * 162;
    const float* cg = controls + (size_t)b * (TSTEPS * 2);

    float u_l = cg[0], u_r = cg[1];

    // ---- prologue: issue terrain loads for t=0 ----
    Ax ax0 = axq(px), axp = axq(px + 0.1f), axm = axq(px - 0.1f);
    Ax ay0 = axq(py), ayp = axq(py + 0.1f), aym = axq(py - 0.1f);
    Iq qc  = issueQ(zb, ax0, ay0);
    Iq qxp = issueQ(zb, axp, ay0);
    Iq qxm = issueQ(zb, axm, ay0);
    Iq qyp = issueQ(zb, ax0, ayp);
    Iq qym = issueQ(zb, ax0, aym);

    #pragma unroll 1
    for (int t = 0; t < TSTEPS; ++t) {
        const int tn = (t + 1 < TSTEPS) ? (t + 1) : t;
        const float u_l_nxt = cg[2 * tn + 0];
        const float u_r_nxt = cg[2 * tn + 1];

        // ---- next positions depend only on carry: compute now, issue next loads ----
        const float rx = px - X, ry = py - Y, rz = pz - Z;
        const float pvnx = VX + (OY * rz - OZ * ry);
        const float pvny = VY + (OZ * rx - OX * rz);
        const float pvnz = VZ + (OX * ry - OY * rx);
        const float pxn = fmaf(pvnx, CRK, px);
        const float pyn = fmaf(pvny, CRK, py);
        const float pzn = fmaf(pvnz, CRK, pz);

        Ax nax0 = axq(pxn), naxp = axq(pxn + 0.1f), naxm = axq(pxn - 0.1f);
        Ax nay0 = axq(pyn), nayp = axq(pyn + 0.1f), naym = axq(pyn - 0.1f);
        Iq nqc  = issueQ(zb, nax0, nay0);
        Iq nqxp = issueQ(zb, naxp, nay0);
        Iq nqxm = issueQ(zb, naxm, nay0);
        Iq nqyp = issueQ(zb, nax0, nayp);
        Iq nqym = issueQ(zb, nax0, naym);

        // ---- consume prefetched terrain for this step ----
        const float z_pt = combineQ(qc);
        const float zpx  = combineQ(qxp);
        const float zmx  = combineQ(qxm);
        const float zpy  = combineQ(qyp);
        const float zmy  = combineQ(qym);

        const float dh = pz - z_pt;
        const bool on = (px >= -6.4f) && (px <= 6.4f) && (py >= -6.4f) && (py <= 6.4f);
        const float contact = ((dh <= 0.0f) && on) ? 1.0f : 0.0f;

        // surface normal (IEEE divisions, exact reference order)
        const float dzdx = (zpx - zmx) / 0.2f;
        const float dzdy = (zpy - zmy) / 0.2f;
        float nx = -dzdx, ny = -dzdy, nz = 1.0f;
        const float nn = sqrtf(nx * nx + ny * ny + nz * nz) + EPSF;
        nx /= nn; ny /= nn; nz /= nn;

        // spring + damping along normal
        const float xd_n = pvx * nx + pvy * ny + pvz * nz;
        const float s_mag = -(K_STIFF * dh + K_DAMP * xd_n);
        const float fsx = s_mag * nx * contact;
        const float fsy = s_mag * ny * contact;
        const float fsz = s_mag * nz * contact;

        const float Nmag = sqrtf(fsx * fsx + fsy * fsy + fsz * fsz);

        // thrust = normalized first column of R
        float tx = R00, ty = R10, tz = R20;
        const float tnn = sqrtf(tx * tx + ty * ty + tz * tz) + EPSF;
        tx /= tnn; ty /= tnn; tz /= tnn;

        // friction (libm tanhf for reference-grade accuracy)
        const float u_sel = is_left ? u_l : u_r;
        const float kn = K_FRIC * Nmag;
        const float ffx = kn * tanhf(u_sel * tx - pvx);
        const float ffy = kn * tanhf(u_sel * ty - pvy);
        const float ffz = kn * tanhf(u_sel * tz - pvz);

        // torque
        const float Fx = fsx + ffx, Fy = fsy + ffy, Fz = fsz + ffz;
        const float tqx = ry * Fz - rz * Fy;
        const float tqy = rz * Fx - rx * Fz;
        const float tqz = rx * Fy - ry * Fx;

        // ---- 16-point reductions ----
        const float Tqx = dpp_sum16(tqx);
        const float Tqy = dpp_sum16(tqy);
        const float Tqz = dpp_sum16(tqz);
        const float Ssx = dpp_sum16(fsx);
        const float Ssy = dpp_sum16(fsy);
        const float Ssz = dpp_sum16(fsz);
        const float Sfx = dpp_sum16(ffx);
        const float Sfy = dpp_sum16(ffy);
        const float Sfz = dpp_sum16(ffz);

        const float odx = i00 * Tqx + i01 * Tqy + i02 * Tqz;
        const float ody = i10 * Tqx + i11 * Tqy + i12 * Tqz;
        const float odz = i20 * Tqx + i21 * Tqy + i22 * Tqz;

        const float Fcx = Ssx * 0.0625f + Sfx * 0.0625f;
        const float Fcy = Ssy * 0.0625f + Sfy * 0.0625f;
        const float Fcz = -392.4f + Ssz * 0.0625f + Sfz * 0.0625f;
        const float axd = Fcx / 40.0f;
        const float ayd = Fcy / 40.0f;
        const float azd = Fcz / 40.0f;

        // integrate
        const float VXn = fmaf(axd, CRK, VX);
        const float VYn = fmaf(ayd, CRK, VY);
        const float VZn = fmaf(azd, CRK, VZ);
        const float Xn = fmaf(VXn, CRK, X);
        const float Yn = fmaf(VYn, CRK, Y);
        const float Zn = fmaf(VZn, CRK, Z);
        const float OXn = fmaf(odx, CRK, OX);
        const float OYn = fmaf(ody, CRK, OY);
        const float OZn = fmaf(odz, CRK, OZ);

        // rotation integration (Rodrigues, libm sin/cos, IEEE divisions)
        const float th = sqrtf(OXn * OXn + OYn * OYn + OZn * OZn);
        const float tpe = th + EPSF;
        const float axn = OXn / tpe, ayn = OYn / tpe, azn = OZn / tpe;
        const float ang = th * 0.01f;
        const float sth = sinf(ang);
        const float cth = 1.0f - cosf(ang);
        const float M00 = 1.0f - (ayn * ayn + azn * azn) * cth;
        const float M01 = -azn * sth + axn * ayn * cth;
        const float M02 =  ayn * sth + axn * azn * cth;
        const float M10 =  azn * sth + axn * ayn * cth;
        const float M11 = 1.0f - (axn * axn + azn * azn) * cth;
        const float M12 = -axn * sth + ayn * azn * cth;
        const float M20 = -ayn * sth + axn * azn * cth;
        const float M21 =  axn * sth + ayn * azn * cth;
        const float M22 = 1.0f - (axn * axn + ayn * ayn) * cth;

        const float nR00 = R00 * M00 + R01 * M10 + R02 * M20;
        const float nR01 = R00 * M01 + R01 * M11 + R02 * M21;
        const float nR02 = R00 * M02 + R01 * M12 + R02 * M22;
        const float nR10 = R10 * M00 + R11 * M10 + R12 * M20;
        const float nR11 = R10 * M01 + R11 * M11 + R12 * M21;
        const float nR12 = R10 * M02 + R11 * M12 + R12 * M22;
        const float nR20 = R20 * M00 + R21 * M10 + R22 * M20;
        const float nR21 = R20 * M01 + R21 * M11 + R22 * M21;
        const float nR22 = R20 * M02 + R21 * M12 + R22 * M22;

        // ---- output ----
        float* ob = outb + (size_t)t * 162;
        if (lane == 0) {
            ob[0] = Xn;  ob[1] = Yn;  ob[2] = Zn;
            ob[3] = VXn; ob[4] = VYn; ob[5] = VZn;
            ob[6] = OXn; ob[7] = OYn; ob[8] = OZn;
            ob[9]  = nR00; ob[10] = nR01; ob[11] = nR02;
            ob[12] = nR10; ob[13] = nR11; ob[14] = nR12;
            ob[15] = nR20; ob[16] = nR21; ob[17] = nR22;
        }
        if (lane < 16) {
            float* o1 = ob + 18 + 3 * lane;
            o1[0] = pxn; o1[1] = pyn; o1[2] = pzn;
            float* o2 = ob + 66 + 3 * lane;
            o2[0] = fsx; o2[1] = fsy; o2[2] = fsz;
            float* o3 = ob + 114 + 3 * lane;
            o3[0] = ffx; o3[1] = ffy; o3[2] = ffz;
        }

        // commit
        X = Xn; Y = Yn; Z = Zn;
        VX = VXn; VY = VYn; VZ = VZn;
        px = pxn; py = pyn; pz = pzn;
        pvx = pvnx; pvy = pvny; pvz = pvnz;
        OX = OXn; OY = OYn; OZ = OZn;
        R00 = nR00; R01 = nR01; R02 = nR02;
        R10 = nR10; R11 = nR11; R12 = nR12;
        R20 = nR20; R21 = nR21; R22 = nR22;
        qc = nqc; qxp = nqxp; qxm = nqxm; qyp = nqyp; qym = nqym;
        u_l = u_l_nxt; u_r = u_r_nxt;
    }
}

extern "C" void kernel_launch(void* const* d_in, const int* in_sizes, int n_in,
                              void* d_out, int out_size, void* d_ws, size_t ws_size,
                              hipStream_t stream) {
    const float* z_grid       = (const float*)d_in[0];
    const float* controls     = (const float*)d_in[1];
    const float* robot_points = (const float*)d_in[2];
    const float* I_inv        = (const float*)d_in[3];
    float* out = (float*)d_out;

    const int B = in_sizes[0] / (HGRID * WGRID);   // 256
    dphys_sim<<<dim3(B), dim3(64), 0, stream>>>(z_grid, controls, robot_points, I_inv, out);
}

// Round 8
// 898.014 us; speedup vs baseline: 1.0250x; 1.0250x over previous
//
#include <hip/hip_runtime.h>
#include <math.h>

#define WGRID 128
#define HGRID 128
#define TSTEPS 500

// 4-round DPP butterfly within each 16-lane row: every lane ends with its row's sum.
// Addition order identical to R1/R4 (bit-exact lineage).
__device__ __forceinline__ float dpp_sum16(float v) {
    int x;
    x = __builtin_amdgcn_update_dpp(0, __float_as_int(v), 0xB1, 0xF, 0xF, true);
    v += __int_as_float(x);
    x = __builtin_amdgcn_update_dpp(0, __float_as_int(v), 0x4E, 0xF, 0xF, true);
    v += __int_as_float(x);
    x = __builtin_amdgcn_update_dpp(0, __float_as_int(v), 0x141, 0xF, 0xF, true);
    v += __int_as_float(x);
    x = __builtin_amdgcn_update_dpp(0, __float_as_int(v), 0x140, 0xF, 0xF, true);
    v += __int_as_float(x);
    return v;
}

// Per-axis interp prep — EXACT R4 numerics (IEEE division by 0.1f).
struct Ax { int i0; float w; };
__device__ __forceinline__ Ax axq(float q) {
    float xi = (q + 6.4f) / 0.1f;
    xi = fminf(fmaxf(xi, 0.0f), 126.0f);
    float f = floorf(xi);
    Ax a; a.i0 = (int)f; a.w = xi - f; return a;
}

// Bilinear query from the XOR-swizzled LDS grid.
// Swizzle is addressing-only: sg[(r<<7) + (c ^ (r&28))] holds grid[r][c].
// Combine expression is EXACTLY R1/R4's combineQ text.
__device__ __forceinline__ float ldsQ(const float* __restrict__ sg, Ax ax, Ax ay) {
    const int r0 = ax.i0, c0 = ay.i0;
    const int m0 = r0 & 28;
    const int m1 = (r0 + 1) & 28;
    const float z00 = sg[(r0 << 7) + (c0 ^ m0)];
    const float z01 = sg[(r0 << 7) + ((c0 + 1) ^ m0)];
    const float z10 = sg[((r0 + 1) << 7) + (c0 ^ m1)];
    const float z11 = sg[((r0 + 1) << 7) + ((c0 + 1) ^ m1)];
    const float wx = ax.w, wy = ay.w;
    const float ox = 1.0f - wx, oy = 1.0f - wy;
    return z00 * ox * oy + z10 * wx * oy + z01 * ox * wy + z11 * wx * wy;
}

extern "C" __global__ __launch_bounds__(64, 1) void dphys_sim(
    const float* __restrict__ z_grid,
    const float* __restrict__ controls,
    const float* __restrict__ robot_points,
    const float* __restrict__ I_inv,
    float* __restrict__ out)
{
    __shared__ float sg[HGRID * WGRID];   // 64 KB, XOR-swizzled layout

    const int b = blockIdx.x;
    const int lane = threadIdx.x;

    // ---- stage grid into LDS with bank swizzle (float4 loads + b128 writes) ----
    {
        const float4* src = (const float4*)(z_grid + (size_t)b * (HGRID * WGRID));
        #pragma unroll 4
        for (int i = lane; i < (HGRID * WGRID) / 4; i += 64) {
            const float4 v = src[i];
            const int row = i >> 5;                 // 32 float4 per row
            const int colblk = (i & 31) << 2;       // multiple of 4
            const int scol = colblk ^ (row & 28);   // keeps low 2 bits -> 16B aligned
            *(float4*)&sg[(row << 7) + scol] = v;
        }
    }

    const float i00 = I_inv[0], i01 = I_inv[1], i02 = I_inv[2];
    const float i10 = I_inv[3], i11 = I_inv[4], i12 = I_inv[5];
    const float i20 = I_inv[6], i21 = I_inv[7], i22 = I_inv[8];

    const int p = lane & 15;
    const float rpx = robot_points[3 * p + 0];
    const float rpy = robot_points[3 * p + 1];
    const float rpz = robot_points[3 * p + 2];

    const float cog_y = dpp_sum16(rpy) * (1.0f / 16.0f);   // exact: ys are +-0.25
    const bool is_left = rpy > cog_y;

    __syncthreads();

    const float K_STIFF = 5000.0f;
    const float K_DAMP  = 894.4271909999159f;   // sqrt(4*40*5000)
    const float K_FRIC  = 0.5f;
    const float EPSF    = 1e-6f;
    const float CRK     = 0.010050166708416667f; // dt*(1+dt/2+dt^2/6+dt^3/24)

    float X = 0.f, Y = 0.f, Z = 1.f;
    float VX = 0.f, VY = 0.f, VZ = 0.f;
    float R00 = 1.f, R01 = 0.f, R02 = 0.f;
    float R10 = 0.f, R11 = 1.f, R12 = 0.f;
    float R20 = 0.f, R21 = 0.f, R22 = 1.f;
    float OX = 0.f, OY = 0.f, OZ = 0.f;
    float px = rpx, py = rpy, pz = rpz + 1.0f;
    float pvx = 0.f, pvy = 0.f, pvz = 0.f;

    float* outb = out + (size_t)b * TSTEPS * 162;
    const float* cg = controls + (size_t)b * (TSTEPS * 2);

    float u_l = cg[0], u_r = cg[1];

    #pragma unroll 2
    for (int t = 0; t < TSTEPS; ++t) {
        const int tn = (t + 1 < TSTEPS) ? (t + 1) : t;
        const float u_l_nxt = cg[2 * tn + 0];
        const float u_r_nxt = cg[2 * tn + 1];

        // ---- terrain queries (R4's deduped axes; LDS reads, same values) ----
        Ax ax0 = axq(px), axp = axq(px + 0.1f), axm = axq(px - 0.1f);
        Ax ay0 = axq(py), ayp = axq(py + 0.1f), aym = axq(py - 0.1f);
        const float z_pt = ldsQ(sg, ax0, ay0);
        const float zpx  = ldsQ(sg, axp, ay0);
        const float zmx  = ldsQ(sg, axm, ay0);
        const float zpy  = ldsQ(sg, ax0, ayp);
        const float zmy  = ldsQ(sg, ax0, aym);

        const float dh = pz - z_pt;
        const bool on = (px >= -6.4f) && (px <= 6.4f) && (py >= -6.4f) && (py <= 6.4f);
        const float contact = ((dh <= 0.0f) && on) ? 1.0f : 0.0f;

        // surface normal (IEEE divisions, exact reference order)
        const float dzdx = (zpx - zmx) / 0.2f;
        const float dzdy = (zpy - zmy) / 0.2f;
        float nx = -dzdx, ny = -dzdy, nz = 1.0f;
        const float nn = sqrtf(nx * nx + ny * ny + nz * nz) + EPSF;
        nx /= nn; ny /= nn; nz /= nn;

        const float xd_n = pvx * nx + pvy * ny + pvz * nz;
        const float s_mag = -(K_STIFF * dh + K_DAMP * xd_n);
        const float fsx = s_mag * nx * contact;
        const float fsy = s_mag * ny * contact;
        const float fsz = s_mag * nz * contact;

        const float Nmag = sqrtf(fsx * fsx + fsy * fsy + fsz * fsz);

        // thrust = normalized first column of R
        float tx = R00, ty = R10, tz = R20;
        const float tnn = sqrtf(tx * tx + ty * ty + tz * tz) + EPSF;
        tx /= tnn; ty /= tnn; tz /= tnn;

        // friction (libm tanhf: accuracy-critical)
        const float u_sel = is_left ? u_l : u_r;
        const float kn = K_FRIC * Nmag;
        const float ffx = kn * tanhf(u_sel * tx - pvx);
        const float ffy = kn * tanhf(u_sel * ty - pvy);
        const float ffz = kn * tanhf(u_sel * tz - pvz);

        // torque
        const float rx = px - X, ry = py - Y, rz = pz - Z;
        const float Fx = fsx + ffx, Fy = fsy + ffy, Fz = fsz + ffz;
        const float tqx = ry * Fz - rz * Fy;
        const float tqy = rz * Fx - rx * Fz;
        const float tqz = rx * Fy - ry * Fx;

        // 16-point reductions (identical order)
        const float Tqx = dpp_sum16(tqx);
        const float Tqy = dpp_sum16(tqy);
        const float Tqz = dpp_sum16(tqz);
        const float Ssx = dpp_sum16(fsx);
        const float Ssy = dpp_sum16(fsy);
        const float Ssz = dpp_sum16(fsz);
        const float Sfx = dpp_sum16(ffx);
        const float Sfy = dpp_sum16(ffy);
        const float Sfz = dpp_sum16(ffz);

        const float odx = i00 * Tqx + i01 * Tqy + i02 * Tqz;
        const float ody = i10 * Tqx + i11 * Tqy + i12 * Tqz;
        const float odz = i20 * Tqx + i21 * Tqy + i22 * Tqz;

        const float Fcx = Ssx * 0.0625f + Sfx * 0.0625f;
        const float Fcy = Ssy * 0.0625f + Sfy * 0.0625f;
        const float Fcz = -392.4f + Ssz * 0.0625f + Sfz * 0.0625f;
        const float axd = Fcx / 40.0f;
        const float ayd = Fcy / 40.0f;
        const float azd = Fcz / 40.0f;

        // xd_points_new from OLD xd, OLD omega
        const float cpx = OY * rz - OZ * ry;
        const float cpy = OZ * rx - OX * rz;
        const float cpz = OX * ry - OY * rx;
        const float pvnx = VX + cpx, pvny = VY + cpy, pvnz = VZ + cpz;

        // integrate
        const float VXn = fmaf(axd, CRK, VX);
        const float VYn = fmaf(ayd, CRK, VY);
        const float VZn = fmaf(azd, CRK, VZ);
        const float Xn = fmaf(VXn, CRK, X);
        const float Yn = fmaf(VYn, CRK, Y);
        const float Zn = fmaf(VZn, CRK, Z);
        const float pxn = fmaf(pvnx, CRK, px);
        const float pyn = fmaf(pvny, CRK, py);
        const float pzn = fmaf(pvnz, CRK, pz);
        const float OXn = fmaf(odx, CRK, OX);
        const float OYn = fmaf(ody, CRK, OY);
        const float OZn = fmaf(odz, CRK, OZ);

        // rotation integration (Rodrigues, libm sin/cos, IEEE divisions)
        const float th = sqrtf(OXn * OXn + OYn * OYn + OZn * OZn);
        const float tpe = th + EPSF;
        const float axn = OXn / tpe, ayn = OYn / tpe, azn = OZn / tpe;
        const float ang = th * 0.01f;
        const float sth = sinf(ang);
        const float cth = 1.0f - cosf(ang);
        const float M00 = 1.0f - (ayn * ayn + azn * azn) * cth;
        const float M01 = -azn * sth + axn * ayn * cth;
        const float M02 =  ayn * sth + axn * azn * cth;
        const float M10 =  azn * sth + axn * ayn * cth;
        const float M11 = 1.0f - (axn * axn + azn * azn) * cth;
        const float M12 = -axn * sth + ayn * azn * cth;
        const float M20 = -ayn * sth + axn * azn * cth;
        const float M21 =  axn * sth + ayn * azn * cth;
        const float M22 = 1.0f - (axn * axn + ayn * ayn) * cth;

        const float nR00 = R00 * M00 + R01 * M10 + R02 * M20;
        const float nR01 = R00 * M01 + R01 * M11 + R02 * M21;
        const float nR02 = R00 * M02 + R01 * M12 + R02 * M22;
        const float nR10 = R10 * M00 + R11 * M10 + R12 * M20;
        const float nR11 = R10 * M01 + R11 * M11 + R12 * M21;
        const float nR12 = R10 * M02 + R11 * M12 + R12 * M22;
        const float nR20 = R20 * M00 + R21 * M10 + R22 * M20;
        const float nR21 = R20 * M01 + R21 * M11 + R22 * M21;
        const float nR22 = R20 * M02 + R21 * M12 + R22 * M22;

        // output
        float* ob = outb + (size_t)t * 162;
        if (lane == 0) {
            ob[0] = Xn;  ob[1] = Yn;  ob[2] = Zn;
            ob[3] = VXn; ob[4] = VYn; ob[5] = VZn;
            ob[6] = OXn; ob[7] = OYn; ob[8] = OZn;
            ob[9]  = nR00; ob[10] = nR01; ob[11] = nR02;
            ob[12] = nR10; ob[13] = nR11; ob[14] = nR12;
            ob[15] = nR20; ob[16] = nR21; ob[17] = nR22;
        }
        if (lane < 16) {
            float* o1 = ob + 18 + 3 * lane;
            o1[0] = pxn; o1[1] = pyn; o1[2] = pzn;
            float* o2 = ob + 66 + 3 * lane;
            o2[0] = fsx; o2[1] = fsy; o2[2] = fsz;
            float* o3 = ob + 114 + 3 * lane;
            o3[0] = ffx; o3[1] = ffy; o3[2] = ffz;
        }

        // commit
        X = Xn; Y = Yn; Z = Zn;
        VX = VXn; VY = VYn; VZ = VZn;
        px = pxn; py = pyn; pz = pzn;
        pvx = pvnx; pvy = pvny; pvz = pvnz;
        OX = OXn; OY = OYn; OZ = OZn;
        R00 = nR00; R01 = nR01; R02 = nR02;
        R10 = nR10; R11 = nR11; R12 = nR12;
        R20 = nR20; R21 = nR21; R22 = nR22;
        u_l = u_l_nxt; u_r = u_r_nxt;
    }
}

extern "C" void kernel_launch(void* const* d_in, const int* in_sizes, int n_in,
                              void* d_out, int out_size, void* d_ws, size_t ws_size,
                              hipStream_t stream) {
    const float* z_grid       = (const float*)d_in[0];
    const float* controls     = (const float*)d_in[1];
    const float* robot_points = (const float*)d_in[2];
    const float* I_inv        = (const float*)d_in[3];
    float* out = (float*)d_out;

    const int B = in_sizes[0] / (HGRID * WGRID);   // 256
    dphys_sim<<<dim3(B), dim3(64), 0, stream>>>(z_grid, controls, robot_points, I_inv, out);
}

// Round 10
// 872.055 us; speedup vs baseline: 1.0556x; 1.0298x over previous
//
#include <hip/hip_runtime.h>
#include <math.h>

#define WGRID 128
#define HGRID 128
#define TSTEPS 500

// 4-round DPP butterfly within each 16-lane row: every lane ends with its row's sum.
// Addition order identical to R1/R4/R8 (bit-exact lineage).
__device__ __forceinline__ float dpp_sum16(float v) {
    int x;
    x = __builtin_amdgcn_update_dpp(0, __float_as_int(v), 0xB1, 0xF, 0xF, true);
    v += __int_as_float(x);
    x = __builtin_amdgcn_update_dpp(0, __float_as_int(v), 0x4E, 0xF, 0xF, true);
    v += __int_as_float(x);
    x = __builtin_amdgcn_update_dpp(0, __float_as_int(v), 0x141, 0xF, 0xF, true);
    v += __int_as_float(x);
    x = __builtin_amdgcn_update_dpp(0, __float_as_int(v), 0x140, 0xF, 0xF, true);
    v += __int_as_float(x);
    return v;
}

// Per-axis interp prep — EXACT R4/R8 numerics (IEEE division by 0.1f).
struct Ax { int i0; float w; };
__device__ __forceinline__ Ax axq(float q) {
    float xi = (q + 6.4f) / 0.1f;
    xi = fminf(fmaxf(xi, 0.0f), 126.0f);
    float f = floorf(xi);
    Ax a; a.i0 = (int)f; a.w = xi - f; return a;
}

// One bilinear query issued from LDS (plain R1 layout: rows contiguous ->
// z00/z01 and z10/z11 pairs are adjacent, compiler merges to ds_read2_b32).
struct Iq { float z00, z01, z10, z11, wx, wy; };
__device__ __forceinline__ Iq issueQ(const float* __restrict__ sg, Ax ax, Ax ay) {
    const float* r0 = sg + (ax.i0 * WGRID + ay.i0);
    Iq q;
    q.z00 = r0[0];
    q.z01 = r0[1];
    q.z10 = r0[WGRID];
    q.z11 = r0[WGRID + 1];
    q.wx = ax.w; q.wy = ay.w;
    return q;
}
// EXACT lineage combine text.
__device__ __forceinline__ float combineQ(Iq q) {
    float ox = 1.0f - q.wx, oy = 1.0f - q.wy;
    return q.z00 * ox * oy + q.z10 * q.wx * oy + q.z01 * ox * q.wy + q.z11 * q.wx * q.wy;
}

extern "C" __global__ __launch_bounds__(64, 1) void dphys_sim(
    const float* __restrict__ z_grid,
    const float* __restrict__ controls,
    const float* __restrict__ robot_points,
    const float* __restrict__ I_inv,
    float* __restrict__ out)
{
    __shared__ float sg[HGRID * WGRID];   // 64 KB, plain row-major (R1 layout)

    const int b = blockIdx.x;
    const int lane = threadIdx.x;

    // ---- stage grid into LDS (R1's plain staging) ----
    {
        const float4* src = (const float4*)(z_grid + (size_t)b * (HGRID * WGRID));
        float4* dst = (float4*)sg;
        #pragma unroll 4
        for (int i = lane; i < (HGRID * WGRID) / 4; i += 64) dst[i] = src[i];
    }

    const float i00 = I_inv[0], i01 = I_inv[1], i02 = I_inv[2];
    const float i10 = I_inv[3], i11 = I_inv[4], i12 = I_inv[5];
    const float i20 = I_inv[6], i21 = I_inv[7], i22 = I_inv[8];

    const int p = lane & 15;
    const float rpx = robot_points[3 * p + 0];
    const float rpy = robot_points[3 * p + 1];
    const float rpz = robot_points[3 * p + 2];

    const float cog_y = dpp_sum16(rpy) * (1.0f / 16.0f);   // exact: ys are +-0.25
    const bool is_left = rpy > cog_y;

    __syncthreads();

    const float K_STIFF = 5000.0f;
    const float K_DAMP  = 894.4271909999159f;   // sqrt(4*40*5000)
    const float K_FRIC  = 0.5f;
    const float EPSF    = 1e-6f;
    const float CRK     = 0.010050166708416667f; // dt*(1+dt/2+dt^2/6+dt^3/24)

    float X = 0.f, Y = 0.f, Z = 1.f;
    float VX = 0.f, VY = 0.f, VZ = 0.f;
    float R00 = 1.f, R01 = 0.f, R02 = 0.f;
    float R10 = 0.f, R11 = 1.f, R12 = 0.f;
    float R20 = 0.f, R21 = 0.f, R22 = 1.f;
    float OX = 0.f, OY = 0.f, OZ = 0.f;
    float px = rpx, py = rpy, pz = rpz + 1.0f;
    float pvx = 0.f, pvy = 0.f, pvz = 0.f;

    float* outb = out + (size_t)b * TSTEPS * 162;
    const float* cg = controls + (size_t)b * (TSTEPS * 2);

    float u_l = cg[0], u_r = cg[1];

    // ---- prologue: issue terrain reads for t=0 (R4 structure, LDS source) ----
    Ax ax0 = axq(px), axp = axq(px + 0.1f), axm = axq(px - 0.1f);
    Ax ay0 = axq(py), ayp = axq(py + 0.1f), aym = axq(py - 0.1f);
    Iq qc  = issueQ(sg, ax0, ay0);
    Iq qxp = issueQ(sg, axp, ay0);
    Iq qxm = issueQ(sg, axm, ay0);
    Iq qyp = issueQ(sg, ax0, ayp);
    Iq qym = issueQ(sg, ax0, aym);

    #pragma unroll 2
    for (int t = 0; t < TSTEPS; ++t) {
        const int tn = (t + 1 < TSTEPS) ? (t + 1) : t;
        const float u_l_nxt = cg[2 * tn + 0];
        const float u_r_nxt = cg[2 * tn + 1];

        // ---- next positions depend only on carry: compute now, issue next reads
        //      (R4's proven pipeline order) ----
        const float rx = px - X, ry = py - Y, rz = pz - Z;
        const float pvnx = VX + (OY * rz - OZ * ry);
        const float pvny = VY + (OZ * rx - OX * rz);
        const float pvnz = VZ + (OX * ry - OY * rx);
        const float pxn = fmaf(pvnx, CRK, px);
        const float pyn = fmaf(pvny, CRK, py);
        const float pzn = fmaf(pvnz, CRK, pz);

        Ax nax0 = axq(pxn), naxp = axq(pxn + 0.1f), naxm = axq(pxn - 0.1f);
        Ax nay0 = axq(pyn), nayp = axq(pyn + 0.1f), naym = axq(pyn - 0.1f);
        Iq nqc  = issueQ(sg, nax0, nay0);
        Iq nqxp = issueQ(sg, naxp, nay0);
        Iq nqxm = issueQ(sg, naxm, nay0);
        Iq nqyp = issueQ(sg, nax0, nayp);
        Iq nqym = issueQ(sg, nax0, naym);

        // ---- consume prefetched terrain (R4 text) ----
        const float z_pt = combineQ(qc);
        const float zpx  = combineQ(qxp);
        const float zmx  = combineQ(qxm);
        const float zpy  = combineQ(qyp);
        const float zmy  = combineQ(qym);

        const float dh = pz - z_pt;
        const bool on = (px >= -6.4f) && (px <= 6.4f) && (py >= -6.4f) && (py <= 6.4f);
        const float contact = ((dh <= 0.0f) && on) ? 1.0f : 0.0f;

        // surface normal (IEEE divisions, exact lineage order)
        const float dzdx = (zpx - zmx) / 0.2f;
        const float dzdy = (zpy - zmy) / 0.2f;
        float nx = -dzdx, ny = -dzdy, nz = 1.0f;
        const float nn = sqrtf(nx * nx + ny * ny + nz * nz) + EPSF;
        nx /= nn; ny /= nn; nz /= nn;

        const float xd_n = pvx * nx + pvy * ny + pvz * nz;
        const float s_mag = -(K_STIFF * dh + K_DAMP * xd_n);
        const float fsx = s_mag * nx * contact;
        const float fsy = s_mag * ny * contact;
        const float fsz = s_mag * nz * contact;

        const float Nmag = sqrtf(fsx * fsx + fsy * fsy + fsz * fsz);

        // thrust = normalized first column of R
        float tx = R00, ty = R10, tz = R20;
        const float tnn = sqrtf(tx * tx + ty * ty + tz * tz) + EPSF;
        tx /= tnn; ty /= tnn; tz /= tnn;

        // friction (libm tanhf: accuracy-critical)
        const float u_sel = is_left ? u_l : u_r;
        const float kn = K_FRIC * Nmag;
        const float ffx = kn * tanhf(u_sel * tx - pvx);
        const float ffy = kn * tanhf(u_sel * ty - pvy);
        const float ffz = kn * tanhf(u_sel * tz - pvz);

        // torque
        const float Fx = fsx + ffx, Fy = fsy + ffy, Fz = fsz + ffz;
        const float tqx = ry * Fz - rz * Fy;
        const float tqy = rz * Fx - rx * Fz;
        const float tqz = rx * Fy - ry * Fx;

        // 16-point reductions (identical order)
        const float Tqx = dpp_sum16(tqx);
        const float Tqy = dpp_sum16(tqy);
        const float Tqz = dpp_sum16(tqz);
        const float Ssx = dpp_sum16(fsx);
        const float Ssy = dpp_sum16(fsy);
        const float Ssz = dpp_sum16(fsz);
        const float Sfx = dpp_sum16(ffx);
        const float Sfy = dpp_sum16(ffy);
        const float Sfz = dpp_sum16(ffz);

        const float odx = i00 * Tqx + i01 * Tqy + i02 * Tqz;
        const float ody = i10 * Tqx + i11 * Tqy + i12 * Tqz;
        const float odz = i20 * Tqx + i21 * Tqy + i22 * Tqz;

        const float Fcx = Ssx * 0.0625f + Sfx * 0.0625f;
        const float Fcy = Ssy * 0.0625f + Sfy * 0.0625f;
        const float Fcz = -392.4f + Ssz * 0.0625f + Sfz * 0.0625f;
        const float axd = Fcx / 40.0f;
        const float ayd = Fcy / 40.0f;
        const float azd = Fcz / 40.0f;

        // integrate
        const float VXn = fmaf(axd, CRK, VX);
        const float VYn = fmaf(ayd, CRK, VY);
        const float VZn = fmaf(azd, CRK, VZ);
        const float Xn = fmaf(VXn, CRK, X);
        const float Yn = fmaf(VYn, CRK, Y);
        const float Zn = fmaf(VZn, CRK, Z);
        const float OXn = fmaf(odx, CRK, OX);
        const float OYn = fmaf(ody, CRK, OY);
        const float OZn = fmaf(odz, CRK, OZ);

        // rotation integration (Rodrigues, libm sin/cos, IEEE divisions)
        const float th = sqrtf(OXn * OXn + OYn * OYn + OZn * OZn);
        const float tpe = th + EPSF;
        const float axn = OXn / tpe, ayn = OYn / tpe, azn = OZn / tpe;
        const float ang = th * 0.01f;
        const float sth = sinf(ang);
        const float cth = 1.0f - cosf(ang);
        const float M00 = 1.0f - (ayn * ayn + azn * azn) * cth;
        const float M01 = -azn * sth + axn * ayn * cth;
        const float M02 =  ayn * sth + axn * azn * cth;
        const float M10 =  azn * sth + axn * ayn * cth;
        const float M11 = 1.0f - (axn * axn + azn * azn) * cth;
        const float M12 = -axn * sth + ayn * azn * cth;
        const float M20 = -ayn * sth + axn * azn * cth;
        const float M21 =  axn * sth + ayn * azn * cth;
        const float M22 = 1.0f - (axn * axn + ayn * ayn) * cth;

        const float nR00 = R00 * M00 + R01 * M10 + R02 * M20;
        const float nR01 = R00 * M01 + R01 * M11 + R02 * M21;
        const float nR02 = R00 * M02 + R01 * M12 + R02 * M22;
        const float nR10 = R10 * M00 + R11 * M10 + R12 * M20;
        const float nR11 = R10 * M01 + R11 * M11 + R12 * M21;
        const float nR12 = R10 * M02 + R11 * M12 + R12 * M22;
        const float nR20 = R20 * M00 + R21 * M10 + R22 * M20;
        const float nR21 = R20 * M01 + R21 * M11 + R22 * M21;
        const float nR22 = R20 * M02 + R21 * M12 + R22 * M22;

        // ---- output (same bits/addresses; lane-0 block packed as float2) ----
        float* ob = outb + (size_t)t * 162;
        if (lane == 0) {
            float2* ob2 = (float2*)ob;   // byte offset 648*t + 81*8*... always 8B-aligned
            ob2[0] = make_float2(Xn,  Yn);
            ob2[1] = make_float2(Zn,  VXn);
            ob2[2] = make_float2(VYn, VZn);
            ob2[3] = make_float2(OXn, OYn);
            ob2[4] = make_float2(OZn, nR00);
            ob2[5] = make_float2(nR01, nR02);
            ob2[6] = make_float2(nR10, nR11);
            ob2[7] = make_float2(nR12, nR20);
            ob2[8] = make_float2(nR21, nR22);
        }
        if (lane < 16) {
            float* o1 = ob + 18 + 3 * lane;
            o1[0] = pxn; o1[1] = pyn; o1[2] = pzn;
            float* o2 = ob + 66 + 3 * lane;
            o2[0] = fsx; o2[1] = fsy; o2[2] = fsz;
            float* o3 = ob + 114 + 3 * lane;
            o3[0] = ffx; o3[1] = ffy; o3[2] = ffz;
        }

        // commit
        X = Xn; Y = Yn; Z = Zn;
        VX = VXn; VY = VYn; VZ = VZn;
        px = pxn; py = pyn; pz = pzn;
        pvx = pvnx; pvy = pvny; pvz = pvnz;
        OX = OXn; OY = OYn; OZ = OZn;
        R00 = nR00; R01 = nR01; R02 = nR02;
        R10 = nR10; R11 = nR11; R12 = nR12;
        R20 = nR20; R21 = nR21; R22 = nR22;
        qc = nqc; qxp = nqxp; qxm = nqxm; qyp = nqyp; qym = nqym;
        u_l = u_l_nxt; u_r = u_r_nxt;
    }
}

extern "C" void kernel_launch(void* const* d_in, const int* in_sizes, int n_in,
                              void* d_out, int out_size, void* d_ws, size_t ws_size,
                              hipStream_t stream) {
    const float* z_grid       = (const float*)d_in[0];
    const float* controls     = (const float*)d_in[1];
    const float* robot_points = (const float*)d_in[2];
    const float* I_inv        = (const float*)d_in[3];
    float* out = (float*)d_out;

    const int B = in_sizes[0] / (HGRID * WGRID);   // 256
    dphys_sim<<<dim3(B), dim3(64), 0, stream>>>(z_grid, controls, robot_points, I_inv, out);
}